// Round 1
// 1207.124 us; speedup vs baseline: 96.8688x; 96.8688x over previous
//
#include <hip/hip_runtime.h>
#include <hip/hip_fp16.h>
#include <stdint.h>

#define N_NODES 50000
#define FIN_D   100
#define E_EDGES 800000
#define NRELS   200
#define B_BATCH 512
#define HDIM    100

__device__ __forceinline__ unsigned short f2bf(float f){
  unsigned int x = __builtin_bit_cast(unsigned int, f);
  unsigned int lsb = (x >> 16) & 1u;
  x += 0x7fffu + lsb;
  return (unsigned short)(x >> 16);
}
// float-tensor load: fdt 2=fp16, 1=bf16, 0=f32
__device__ __forceinline__ float ldf(const void* p, size_t i, int fdt){
  if (fdt == 2) return __half2float(((const __half*)p)[i]);
  if (fdt == 1){ unsigned int x = ((unsigned int)((const unsigned short*)p)[i]) << 16;
                 return __builtin_bit_cast(float, x); }
  return ((const float*)p)[i];
}
// output store, same dtype as inputs
__device__ __forceinline__ void stf(void* p, size_t i, float v, int fdt){
  if (fdt == 2) ((__half*)p)[i] = __float2half_rn(v);
  else if (fdt == 1) ((unsigned short*)p)[i] = f2bf(v);
  else ((float*)p)[i] = v;
}
// integer-tensor load: i64 flag
__device__ __forceinline__ int ild(const void* p, size_t i, int i64){
  return i64 ? (int)((const long long*)p)[i] : ((const int*)p)[i];
}

// ---------------- dtype probes ----------------
__global__ void k_probe(const unsigned short* __restrict__ eh, const unsigned int* __restrict__ ew,
                        const unsigned int* __restrict__ elw, int* __restrict__ ifl){
  int t = threadIdx.x;   // 64 lanes
  int cF = 0, cB = 0, c32 = 0;
  #pragma unroll
  for (int j = 0; j < 4; ++j){
    unsigned short u = eh[4*t + j];
    {
      int e5 = (u >> 10) & 31, m = u & 1023;
      float v = (e5 == 0) ? ldexpf((float)m, -24) : ldexpf(1.f + m/1024.f, e5 - 15);
      if (v >= 0.004f && v <= 0.30f) cF++;
    }
    {
      unsigned int x = ((unsigned int)(u & 0x7FFF)) << 16;
      float v = __builtin_bit_cast(float, x);
      if (v >= 0.004f && v <= 0.30f) cB++;
    }
  }
  #pragma unroll
  for (int j = 0; j < 2; ++j){
    unsigned int w = ew[2*t + j] & 0x7FFFFFFFu;
    float v = __builtin_bit_cast(float, w);
    if (v >= 0.004f && v <= 0.30f) c32++;
  }
  for (int o = 1; o < 64; o <<= 1){
    cF += __shfl_xor(cF, o); cB += __shfl_xor(cB, o); c32 += __shfl_xor(c32, o);
  }
  int z = (elw[2*t + 1] == 0u) ? 1 : 0;
  unsigned long long mb = __ballot(z);
  if (t == 0){
    int fdt;
    if (c32 >= 96) fdt = 0;
    else fdt = (cB > cF) ? 1 : 2;
    ifl[1] = fdt;
    ifl[0] = (__popcll(mb) >= 60) ? 1 : 0;
  }
}

// ---------------- setup ----------------
__global__ void k_fillm(int* __restrict__ p, int v, int n){
  int i = blockIdx.x * blockDim.x + threadIdx.x;
  if (i < n) p[i] = v;
}
__global__ void k_cvtb(const void* __restrict__ binp, const int* __restrict__ ifl, int* __restrict__ b32){
  int i = blockIdx.x*256 + threadIdx.x;
  if (i >= B_BATCH*4) return;
  b32[i] = ild(binp, i, ifl[0]);
}
__global__ void k_mset(const int* __restrict__ b32, int* __restrict__ midx){
  int i = blockIdx.x*256 + threadIdx.x;
  if (i >= B_BATCH) return;
  midx[b32[i*4 + 2]] = i;
}
// M2f[r][j] = rtab[edge_type[r]] @ W_rel
__global__ void k_m2f(const void* __restrict__ rtab, const void* __restrict__ wrel,
                      const void* __restrict__ et, const int* __restrict__ ifl, float* __restrict__ M2){
  int idx = blockIdx.x*256 + threadIdx.x;
  if (idx >= 200*200) return;
  int fdt = ifl[1];
  int r = idx / 200, j = idx % 200;
  int g = ild(et, r, ifl[0]);
  float s = 0.f;
  for (int k = 0; k < 100; ++k) s += ldf(rtab, (size_t)g*100 + k, fdt) * ldf(wrel, (size_t)k*200 + j, fdt);
  M2[idx] = s;
}

// transpose attention matrices into coalesced-friendly f32 layouts
__global__ void k_trans(const void* __restrict__ ah, const void* __restrict__ aout,
                        const void* __restrict__ a2h, const void* __restrict__ a2o,
                        const int* __restrict__ ifl,
                        float* __restrict__ aTs, float* __restrict__ aTd,
                        float* __restrict__ aoTs, float* __restrict__ aoTd,
                        float* __restrict__ a2f, float* __restrict__ a2of){
  int i = blockIdx.x*256 + threadIdx.x;
  int fdt = ifl[1];
  if (i < 20000){ int k=i/200, t=i%200; aTs[i] = ldf(ah,(size_t)t*300+k,fdt); return; }
  i -= 20000;
  if (i < 20000){ int k=i/200, t=i%200; aTd[i] = ldf(ah,(size_t)t*300+100+k,fdt); return; }
  i -= 20000;
  if (i < 40000){ int k=i/200, t=i%200; aoTs[i] = ldf(aout,(size_t)t*600+k,fdt); return; }
  i -= 40000;
  if (i < 40000){ int k=i/200, t=i%200; aoTd[i] = ldf(aout,(size_t)t*600+200+k,fdt); return; }
  i -= 40000;
  if (i < 200){ a2f[i] = ldf(a2h, i, fdt); return; }
  i -= 200;
  if (i < 200){ a2of[i] = ldf(a2o, i, fdt); return; }
}

// R1f[tt][t] = rtab[tt] @ a_rel.T ; sR1[tt][h] = (R1f[tt] * a2)_head-sums
__global__ __launch_bounds__(256)
void k_R1(const void* __restrict__ rtab, const void* __restrict__ ah, const int* __restrict__ ifl,
          const float* __restrict__ a2f, float* __restrict__ R1f, float* __restrict__ sR1){
  __shared__ float rt[100], ml[200];
  const int tt = blockIdx.x, t = threadIdx.x, fdt = ifl[1];
  if (t < 100) rt[t] = ldf(rtab,(size_t)tt*100+t,fdt);
  __syncthreads();
  if (t < 200){
    float R = 0.f;
    for (int k = 0; k < 100; ++k) R += rt[k]*ldf(ah,(size_t)t*300+200+k,fdt);
    R1f[tt*200+t] = R; ml[t] = R*a2f[t];
  }
  __syncthreads();
  if (t < 64){
    float s = 0.f;
    for (int q = t; q < 100; q += 64) s += ml[q];
    for (int o = 1; o < 64; o <<= 1) s += __shfl_xor(s, o);
    if (t == 0) sR1[tt*2] = s;
  } else if (t < 128){
    int l = t - 64;
    float s = 0.f;
    for (int q = 100 + l; q < 200; q += 64) s += ml[q];
    for (int o = 1; o < 64; o <<= 1) s += __shfl_xor(s, o);
    if (l == 0) sR1[tt*2+1] = s;
  }
}

// R2f[tt][t] = M2f[tt] @ a_rel2.T ; sR2[tt] = R2f[tt]·a2o
__global__ __launch_bounds__(256)
void k_R2(const float* __restrict__ M2f, const void* __restrict__ aout, const int* __restrict__ ifl,
          const float* __restrict__ a2of, float* __restrict__ R2f, float* __restrict__ sR2){
  __shared__ float mr[200], ml[200];
  const int tt = blockIdx.x, t = threadIdx.x, fdt = ifl[1];
  if (t < 200) mr[t] = M2f[tt*200+t];
  __syncthreads();
  if (t < 200){
    float R = 0.f;
    for (int k = 0; k < 200; ++k) R += mr[k]*ldf(aout,(size_t)t*600+400+k,fdt);
    R2f[tt*200+t] = R; ml[t] = R*a2of[t];
  }
  __syncthreads();
  if (t < 64){
    float s = 0.f;
    for (int q = t; q < 200; q += 64) s += ml[q];
    for (int o = 1; o < 64; o <<= 1) s += __shfl_xor(s, o);
    if (t == 0) sR2[tt] = s;
  }
}

// ---------------- CSR (packed: dst | type<<16) ----------------
__global__ void k_count(const void* __restrict__ el, const int* __restrict__ ifl, int* __restrict__ cnt){
  int e = blockIdx.x*256 + threadIdx.x;
  if (e >= E_EDGES) return;
  atomicAdd(&cnt[ild(el, e, ifl[0])], 1);
}
__global__ __launch_bounds__(256)
void k_scan(const int* __restrict__ cnt, int* __restrict__ offs){
  __shared__ int bs[256];
  int t = threadIdx.x;
  const int CH = (N_NODES + 255) / 256;
  int lo = t*CH, hi = min(lo+CH, N_NODES);
  int s = 0;
  for (int i = lo; i < hi; ++i) s += cnt[i];
  bs[t] = s;
  __syncthreads();
  for (int o = 1; o < 256; o <<= 1){
    int v = (t >= o) ? bs[t-o] : 0;
    __syncthreads();
    bs[t] += v;
    __syncthreads();
  }
  int base = (t == 0) ? 0 : bs[t-1];
  for (int i = lo; i < hi; ++i){ offs[i] = base; base += cnt[i]; }
  if (t == 255) offs[N_NODES] = bs[255];
}
__global__ void k_scatter(const void* __restrict__ el, const void* __restrict__ et,
                          const int* __restrict__ ifl, const int* __restrict__ offs,
                          int* __restrict__ fill, int* __restrict__ csr){
  int e = blockIdx.x*256 + threadIdx.x;
  if (e >= E_EDGES) return;
  int f = ifl[0];
  int a = ild(el, e, f);
  int pos = offs[a] + atomicAdd(&fill[a], 1);
  csr[pos] = ild(el, (size_t)E_EDGES + e, f) | (ild(et, e, f) << 16);
}

// flag = masked nodes + their neighbors (only nodes whose x1 is ever consumed)
__global__ void k_flag(const int* __restrict__ b32, const int* __restrict__ offs,
                       const int* __restrict__ csr, int* __restrict__ nflag){
  const int i = blockIdx.x, t = threadIdx.x;
  const int n = b32[i*4 + 2];
  if (t == 0) nflag[n] = 1;
  for (int j = offs[n] + t; j < offs[n+1]; j += 256) nflag[csr[j] & 0xFFFF] = 1;
}

// D1[n][t] = ent[n] @ a_dst.T (fp16) ; sD[n][h] = head-sums of D1*a2
__global__ __launch_bounds__(256)
void k_D1(const void* __restrict__ ent, const int* __restrict__ ifl, const float* __restrict__ aTd,
          const float* __restrict__ a2f, __half* __restrict__ D1, float* __restrict__ sD){
  __shared__ float en[100], ml[200];
  const int n = blockIdx.x, t = threadIdx.x, fdt = ifl[1];
  if (t < 100) en[t] = ldf(ent, (size_t)n*100 + t, fdt);
  __syncthreads();
  if (t < 200){
    float d = 0.f;
    for (int k = 0; k < 100; ++k) d += en[k]*aTd[k*200+t];
    D1[(size_t)n*200+t] = __float2half_rn(d); ml[t] = d*a2f[t];
  }
  __syncthreads();
  if (t < 64){
    float s = 0.f;
    for (int q = t; q < 100; q += 64) s += ml[q];
    for (int o = 1; o < 64; o <<= 1) s += __shfl_xor(s, o);
    if (t == 0) sD[(size_t)n*2] = s;
  } else if (t < 128){
    int l = t - 64;
    float s = 0.f;
    for (int q = 100 + l; q < 200; q += 64) s += ml[q];
    for (int o = 1; o < 64; o <<= 1) s += __shfl_xor(s, o);
    if (l == 0) sD[(size_t)n*2+1] = s;
  }
}

// layer 1 aggregation, flagged nodes only; edge loop is sync-free & coalesced
__global__ __launch_bounds__(256)
void k_x1(const void* __restrict__ ent, const int* __restrict__ ifl, const int* __restrict__ nflag,
          const float* __restrict__ aTs, const float* __restrict__ a2f,
          const float* __restrict__ R1f, const float* __restrict__ sR1,
          const __half* __restrict__ D1, const float* __restrict__ sD,
          const int* __restrict__ offs, const int* __restrict__ csr, __half* __restrict__ x1)
{
  __shared__ float en[100], ml[200], sS2[2];
  const int n = blockIdx.x, t = threadIdx.x;
  if (!nflag[n]) return;
  const int fdt = ifl[1];
  if (t < 100) en[t] = ldf(ent, (size_t)n*100 + t, fdt);
  __syncthreads();
  float S = 0.f;
  if (t < 200){
    for (int k = 0; k < 100; ++k) S += en[k]*aTs[k*200+t];
    ml[t] = S*a2f[t];
  }
  __syncthreads();
  if (t < 64){
    float s = 0.f;
    for (int q = t; q < 100; q += 64) s += ml[q];
    for (int o = 1; o < 64; o <<= 1) s += __shfl_xor(s, o);
    if (t == 0) sS2[0] = s;
  } else if (t < 128){
    int l = t - 64;
    float s = 0.f;
    for (int q = 100 + l; q < 200; q += 64) s += ml[q];
    for (int o = 1; o < 64; o <<= 1) s += __shfl_xor(s, o);
    if (l == 0) sS2[1] = s;
  }
  __syncthreads();
  if (t >= 200) return;
  const int h = (t >= 100) ? 1 : 0;
  const float sS = sS2[h];
  float acc = 0.f, W = 0.f;
  const int beg = offs[n], end = offs[n+1];
  for (int j = beg; j < end; ++j){
    int pk = csr[j];
    int v = pk & 0xFFFF, tt = pk >> 16;
    float d = __half2float(D1[(size_t)v*200 + t]);
    float r = R1f[tt*200 + t];
    float p = sS + sD[(size_t)v*2 + h] + sR1[tt*2 + h];
    float lk = p > 0.f ? p : 0.2f*p;
    float w = expf(-lk);
    acc += w*(d + r); W += w;
  }
  float hh = (S*W + acc) / (W + 1e-12f);
  x1[(size_t)n*200 + t] = __float2half_rn(hh > 0.f ? hh : (expf(hh) - 1.f));
}

// D2[n][t] = x1[n] @ a_dst2.T (fp16, flagged only) ; sD2[n] = D2·a2o
__global__ __launch_bounds__(256)
void k_D2(const __half* __restrict__ x1, const int* __restrict__ nflag, const float* __restrict__ aoTd,
          const float* __restrict__ a2of, __half* __restrict__ D2, float* __restrict__ sD2){
  __shared__ float xn[200], ml[200];
  const int n = blockIdx.x, t = threadIdx.x;
  if (!nflag[n]) return;
  if (t < 200) xn[t] = __half2float(x1[(size_t)n*200 + t]);
  __syncthreads();
  if (t < 200){
    float d = 0.f;
    for (int k = 0; k < 200; ++k) d += xn[k]*aoTd[k*200+t];
    D2[(size_t)n*200+t] = __float2half_rn(d); ml[t] = d*a2of[t];
  }
  __syncthreads();
  if (t < 64){
    float s = 0.f;
    for (int q = t; q < 200; q += 64) s += ml[q];
    for (int o = 1; o < 64; o <<= 1) s += __shfl_xor(s, o);
    if (t == 0) sD2[n] = s;
  }
}

// layer 2, masked nodes only
__global__ __launch_bounds__(256)
void k_x2m(const int* __restrict__ b32, const __half* __restrict__ x1, const float* __restrict__ aoTs,
           const float* __restrict__ a2of, const float* __restrict__ R2f, const float* __restrict__ sR2,
           const __half* __restrict__ D2, const float* __restrict__ sD2,
           const int* __restrict__ offs, const int* __restrict__ csr, float* __restrict__ x2m)
{
  __shared__ float xn[200], ml[200], sS2[1];
  const int i = blockIdx.x, t = threadIdx.x;
  const int n = b32[i*4 + 2];
  if (t < 200) xn[t] = __half2float(x1[(size_t)n*200 + t]);
  __syncthreads();
  float S = 0.f;
  if (t < 200){
    for (int k = 0; k < 200; ++k) S += xn[k]*aoTs[k*200+t];
    ml[t] = S*a2of[t];
  }
  __syncthreads();
  if (t < 64){
    float s = 0.f;
    for (int q = t; q < 200; q += 64) s += ml[q];
    for (int o = 1; o < 64; o <<= 1) s += __shfl_xor(s, o);
    if (t == 0) sS2[0] = s;
  }
  __syncthreads();
  if (t >= 200) return;
  const float sS = sS2[0];
  float acc = 0.f, W = 0.f;
  const int beg = offs[n], end = offs[n+1];
  for (int j = beg; j < end; ++j){
    int pk = csr[j];
    int v = pk & 0xFFFF, tt = pk >> 16;
    float d = __half2float(D2[(size_t)v*200 + t]);
    float r = R2f[tt*200 + t];
    float p = sS + sD2[v] + sR2[tt];
    float lk = p > 0.f ? p : 0.2f*p;
    float w = expf(-lk);
    acc += w*(d + r); W += w;
  }
  float hh = (S*W + acc) / (W + 1e-12f);
  x2m[(size_t)i*200 + t] = hh > 0.f ? hh : (expf(hh) - 1.f);
}

// ---------------- epilogue ----------------
__global__ __launch_bounds__(256)
void k_euf(const void* __restrict__ ent, const void* __restrict__ went, const int* __restrict__ ifl,
           const int* __restrict__ midx, const float* __restrict__ x2m, char* __restrict__ dout)
{
  __shared__ float en[100], cl[200], red[1];
  const int n = blockIdx.x, t = threadIdx.x;
  const int fdt = ifl[1];
  if (t < 100) en[t] = ldf(ent, (size_t)n*100 + t, fdt);
  __syncthreads();
  if (t < 64){
    float s = 0.f;
    for (int q = t; q < 100; q += 64) s += en[q]*en[q];
    for (int o = 1; o < 64; o <<= 1) s += __shfl_xor(s, o);
    if (t == 0) red[0] = s;
  }
  __syncthreads();
  const float invn = 1.f / fmaxf(sqrtf(red[0]), 1e-12f);
  const int mi = midx[n];
  float row = 0.f;
  if (t < 200){
    float eu = 0.f;
    for (int k = 0; k < 100; ++k) eu += en[k] * ldf(went, (size_t)k*200 + t, fdt);
    row = eu * invn;
    if (mi >= 0) row += x2m[(size_t)mi*200 + t];
    cl[t] = row * row;
  }
  __syncthreads();
  if (t < 64){
    float s = 0.f;
    for (int q = t; q < 200; q += 64) s += cl[q];
    for (int o = 1; o < 64; o <<= 1) s += __shfl_xor(s, o);
    if (t == 0) red[0] = s;
  }
  __syncthreads();
  if (t < 200){
    float r = 1.f / fmaxf(sqrtf(red[0]), 1e-12f);
    stf(dout, (size_t)n*200 + t, row * r, fdt);
  }
}

// ---------------- his_temp ----------------
__global__ __launch_bounds__(256)
void k_his(const void* __restrict__ binp, const void* __restrict__ wt, const void* __restrict__ bt,
           const int* __restrict__ ifl, char* __restrict__ dout)
{
  __shared__ float he[100];
  const int i = blockIdx.x, t = threadIdx.x;
  const int fdt = ifl[1];
  const size_t esz = (fdt == 0) ? 4 : 2;
  const double t2 = (double)ild(binp, (size_t)i*4 + 3, ifl[0]);
  if (t < 100){
    double a = t2 * (double)ldf(wt, t, fdt) + (double)ldf(bt, t, fdt);
    he[t] = (float)cos(a);
  }
  __syncthreads();
  void* out2 = dout + (size_t)10000000 * esz;
  const size_t base = (size_t)i * (B_BATCH*HDIM);
  for (int s = t; s < B_BATCH*HDIM; s += 256) stf(out2, base + s, he[s % 100], fdt);
}

// ---------------- launch ----------------
extern "C" void kernel_launch(void* const* d_in, const int* in_sizes, int n_in,
                              void* d_out, int out_size, void* d_ws, size_t ws_size,
                              hipStream_t stream)
{
  (void)in_sizes; (void)n_in; (void)out_size; (void)ws_size;
  const void* ent  = d_in[0];
  const void* rtab = d_in[1];
  const void* w_t2 = d_in[2];
  const void* b_t2 = d_in[3];
  const void* Went = d_in[4];
  const void* ah   = d_in[5];
  const void* a2h  = d_in[6];
  const void* Wrel = d_in[7];
  const void* aout = d_in[8];
  const void* a2o  = d_in[9];
  const void* elist = d_in[10];
  const void* etype = d_in[11];
  const void* binp  = d_in[12];

  int* ifl = (int*)d_ws;                         // [0]=int64 flag, [1]=float dtype
  int* b32 = (int*)((char*)d_ws + 256);          // 2048 ints

  char* dout = (char*)d_out;
  // Region A [20MB,40MB): D1 then D2 (fp16, 20,000,000 B exactly).
  //  - fp16 out: inside out1, rewritten by k_his (last).
  //  - f32 out: inside out0, but D1/D2 dead before k_euf writes out0.
  __half* D12 = (__half*)(dout + 20000000);
  // Region B [40MB,~66MB): consumed by kernels up to k_euf; inside out1 for all dtypes.
  char* scr = dout + 40000000;
  size_t cur = 0;
  auto alloc = [&](size_t bytes) -> char* {
    char* p = scr + cur;
    cur = (cur + bytes + 255) & ~(size_t)255;
    return p;
  };
  __half* X1   = (__half*)alloc((size_t)N_NODES*200*2);   // 20 MB
  int*   csr   = (int*)alloc((size_t)E_EDGES*4);          // 3.2 MB
  int*   offs  = (int*)alloc((size_t)(N_NODES+1)*4);
  int*   cnt   = (int*)alloc((size_t)N_NODES*4);
  int*   midx  = (int*)alloc((size_t)N_NODES*4);
  int*   nflag = (int*)alloc((size_t)N_NODES*4);
  float* M2f   = (float*)alloc((size_t)200*200*4);
  float* x2m   = (float*)alloc((size_t)B_BATCH*200*4);
  float* aTs   = (float*)alloc((size_t)100*200*4);
  float* aTd   = (float*)alloc((size_t)100*200*4);
  float* aoTs  = (float*)alloc((size_t)200*200*4);
  float* aoTd  = (float*)alloc((size_t)200*200*4);
  float* R1f   = (float*)alloc((size_t)200*200*4);
  float* R2f   = (float*)alloc((size_t)200*200*4);
  float* sD    = (float*)alloc((size_t)N_NODES*2*4);
  float* sD2   = (float*)alloc((size_t)N_NODES*4);
  float* sR1   = (float*)alloc((size_t)200*2*4);
  float* sR2   = (float*)alloc((size_t)200*4);
  float* a2f   = (float*)alloc((size_t)200*4);
  float* a2of  = (float*)alloc((size_t)200*4);
  // total ~26.1 MB -> ends ~66.1 MB < 72.43 MB (min d_out at esize=2)

  const int EB = (E_EDGES + 255) / 256;
  const int NB = (N_NODES + 255) / 256;

  k_probe<<<dim3(1), dim3(64), 0, stream>>>((const unsigned short*)ent, (const unsigned int*)ent,
                                            (const unsigned int*)elist, ifl);
  k_cvtb <<<dim3(8), dim3(256), 0, stream>>>(binp, ifl, b32);
  k_fillm<<<dim3(NB), dim3(256), 0, stream>>>(midx, -1, N_NODES);
  k_mset <<<dim3(2), dim3(256), 0, stream>>>(b32, midx);
  k_trans<<<dim3(471), dim3(256), 0, stream>>>(ah, aout, a2h, a2o, ifl, aTs, aTd, aoTs, aoTd, a2f, a2of);
  k_m2f  <<<dim3(157), dim3(256), 0, stream>>>(rtab, Wrel, etype, ifl, M2f);
  k_R1   <<<dim3(200), dim3(256), 0, stream>>>(rtab, ah, ifl, a2f, R1f, sR1);
  k_R2   <<<dim3(200), dim3(256), 0, stream>>>(M2f, aout, ifl, a2of, R2f, sR2);

  k_fillm<<<dim3(NB), dim3(256), 0, stream>>>(cnt, 0, N_NODES);
  k_count<<<dim3(EB), dim3(256), 0, stream>>>(elist, ifl, cnt);
  k_scan <<<dim3(1), dim3(256), 0, stream>>>(cnt, offs);
  k_fillm<<<dim3(NB), dim3(256), 0, stream>>>(cnt, 0, N_NODES);
  k_scatter<<<dim3(EB), dim3(256), 0, stream>>>(elist, etype, ifl, offs, cnt, csr);

  k_fillm<<<dim3(NB), dim3(256), 0, stream>>>(nflag, 0, N_NODES);
  k_flag <<<dim3(B_BATCH), dim3(256), 0, stream>>>(b32, offs, csr, nflag);

  k_D1 <<<dim3(N_NODES), dim3(256), 0, stream>>>(ent, ifl, aTd, a2f, D12, sD);
  k_x1 <<<dim3(N_NODES), dim3(256), 0, stream>>>(ent, ifl, nflag, aTs, a2f, R1f, sR1, D12, sD, offs, csr, X1);
  k_D2 <<<dim3(N_NODES), dim3(256), 0, stream>>>(X1, nflag, aoTd, a2of, D12, sD2);
  k_x2m<<<dim3(B_BATCH), dim3(256), 0, stream>>>(b32, X1, aoTs, a2of, R2f, sR2, D12, sD2, offs, csr, x2m);
  k_euf<<<dim3(N_NODES), dim3(256), 0, stream>>>(ent, Went, ifl, midx, x2m, dout);

  // LAST: overwrites all of out1 (incl. all scratch); reads only inputs + ifl
  k_his<<<dim3(B_BATCH), dim3(256), 0, stream>>>(binp, w_t2, b_t2, ifl, dout);
}

// Round 2
// 998.166 us; speedup vs baseline: 117.1475x; 1.2093x over previous
//
#include <hip/hip_runtime.h>
#include <hip/hip_fp16.h>
#include <stdint.h>

#define N_NODES 50000
#define FIN_D   100
#define E_EDGES 800000
#define NRELS   200
#define B_BATCH 512
#define HDIM    100

__device__ __forceinline__ unsigned short f2bf(float f){
  unsigned int x = __builtin_bit_cast(unsigned int, f);
  unsigned int lsb = (x >> 16) & 1u;
  x += 0x7fffu + lsb;
  return (unsigned short)(x >> 16);
}
// float-tensor load: fdt 2=fp16, 1=bf16, 0=f32
__device__ __forceinline__ float ldf(const void* p, size_t i, int fdt){
  if (fdt == 2) return __half2float(((const __half*)p)[i]);
  if (fdt == 1){ unsigned int x = ((unsigned int)((const unsigned short*)p)[i]) << 16;
                 return __builtin_bit_cast(float, x); }
  return ((const float*)p)[i];
}
// output store, same dtype as inputs
__device__ __forceinline__ void stf(void* p, size_t i, float v, int fdt){
  if (fdt == 2) ((__half*)p)[i] = __float2half_rn(v);
  else if (fdt == 1) ((unsigned short*)p)[i] = f2bf(v);
  else ((float*)p)[i] = v;
}
// integer-tensor load: i64 flag
__device__ __forceinline__ int ild(const void* p, size_t i, int i64){
  return i64 ? (int)((const long long*)p)[i] : ((const int*)p)[i];
}

// block-wide reduce of C per-thread values -> outr[C] in LDS (synced)
template<int C>
__device__ __forceinline__ void blockRed(float* v, float* scr /*[4*C]*/, float* outr /*[C]*/){
  #pragma unroll
  for (int i = 0; i < C; ++i){
    #pragma unroll
    for (int o = 1; o < 64; o <<= 1) v[i] += __shfl_xor(v[i], o);
  }
  const int w = threadIdx.x >> 6, l = threadIdx.x & 63;
  if (l == 0){
    #pragma unroll
    for (int i = 0; i < C; ++i) scr[w*C + i] = v[i];
  }
  __syncthreads();
  if ((int)threadIdx.x < C)
    outr[threadIdx.x] = scr[threadIdx.x] + scr[C+threadIdx.x] + scr[2*C+threadIdx.x] + scr[3*C+threadIdx.x];
  __syncthreads();
}

// ---------------- dtype probes ----------------
__global__ void k_probe(const unsigned short* __restrict__ eh, const unsigned int* __restrict__ ew,
                        const unsigned int* __restrict__ elw, int* __restrict__ ifl){
  int t = threadIdx.x;   // 64 lanes
  int cF = 0, cB = 0, c32 = 0;
  #pragma unroll
  for (int j = 0; j < 4; ++j){
    unsigned short u = eh[4*t + j];
    {
      int e5 = (u >> 10) & 31, m = u & 1023;
      float v = (e5 == 0) ? ldexpf((float)m, -24) : ldexpf(1.f + m/1024.f, e5 - 15);
      if (v >= 0.004f && v <= 0.30f) cF++;
    }
    {
      unsigned int x = ((unsigned int)(u & 0x7FFF)) << 16;
      float v = __builtin_bit_cast(float, x);
      if (v >= 0.004f && v <= 0.30f) cB++;
    }
  }
  #pragma unroll
  for (int j = 0; j < 2; ++j){
    unsigned int w = ew[2*t + j] & 0x7FFFFFFFu;
    float v = __builtin_bit_cast(float, w);
    if (v >= 0.004f && v <= 0.30f) c32++;
  }
  for (int o = 1; o < 64; o <<= 1){
    cF += __shfl_xor(cF, o); cB += __shfl_xor(cB, o); c32 += __shfl_xor(c32, o);
  }
  int z = (elw[2*t + 1] == 0u) ? 1 : 0;
  unsigned long long mb = __ballot(z);
  if (t == 0){
    int fdt;
    if (c32 >= 96) fdt = 0;
    else fdt = (cB > cF) ? 1 : 2;
    ifl[1] = fdt;
    ifl[0] = (__popcll(mb) >= 60) ? 1 : 0;
  }
}

// ---------------- setup ----------------
__global__ void k_fillm(int* __restrict__ p, int v, int n){
  int i = blockIdx.x * blockDim.x + threadIdx.x;
  if (i < n) p[i] = v;
}
__global__ void k_cvtb(const void* __restrict__ binp, const int* __restrict__ ifl, int* __restrict__ b32){
  int i = blockIdx.x*256 + threadIdx.x;
  if (i >= B_BATCH*4) return;
  b32[i] = ild(binp, i, ifl[0]);
}
__global__ void k_mset(const int* __restrict__ b32, int* __restrict__ midx){
  int i = blockIdx.x*256 + threadIdx.x;
  if (i >= B_BATCH) return;
  midx[b32[i*4 + 2]] = i;
}
// M2f[r][j] = rtab[edge_type[r]] @ W_rel
__global__ void k_m2f(const void* __restrict__ rtab, const void* __restrict__ wrel,
                      const void* __restrict__ et, const int* __restrict__ ifl, float* __restrict__ M2){
  int idx = blockIdx.x*256 + threadIdx.x;
  if (idx >= 200*200) return;
  int fdt = ifl[1];
  int r = idx / 200, j = idx % 200;
  int g = ild(et, r, ifl[0]);
  float s = 0.f;
  for (int k = 0; k < 100; ++k) s += ldf(rtab, (size_t)g*100 + k, fdt) * ldf(wrel, (size_t)k*200 + j, fdt);
  M2[idx] = s;
}

// transpose attention matrices into coalesced-friendly f32 layouts
__global__ void k_trans(const void* __restrict__ ah, const void* __restrict__ aout,
                        const void* __restrict__ a2h, const void* __restrict__ a2o,
                        const int* __restrict__ ifl,
                        float* __restrict__ aTs, float* __restrict__ aoTs,
                        float* __restrict__ a2f, float* __restrict__ a2of){
  int i = blockIdx.x*256 + threadIdx.x;
  int fdt = ifl[1];
  if (i < 20000){ int k=i/200, t=i%200; aTs[i] = ldf(ah,(size_t)t*300+k,fdt); return; }
  i -= 20000;
  if (i < 40000){ int k=i/200, t=i%200; aoTs[i] = ldf(aout,(size_t)t*600+k,fdt); return; }
  i -= 40000;
  if (i < 200){ a2f[i] = ldf(a2h, i, fdt); return; }
  i -= 200;
  if (i < 200){ a2of[i] = ldf(a2o, i, fdt); return; }
}

// fp16 weight tables (layout [k*200+t]) for the LDS-staged matvec kernels
__global__ void k_w16(const void* __restrict__ went, const void* __restrict__ ah,
                      const void* __restrict__ aout, const int* __restrict__ ifl,
                      __half* __restrict__ W16e, __half* __restrict__ W16d, __half* __restrict__ W16d2){
  int i = blockIdx.x*256 + threadIdx.x;
  int fdt = ifl[1];
  if (i < 20000){ W16e[i] = __float2half_rn(ldf(went, i, fdt)); return; }
  i -= 20000;
  if (i < 20000){ int k=i/200, c=i%200; W16d[i] = __float2half_rn(ldf(ah,(size_t)c*300+100+k,fdt)); return; }
  i -= 20000;
  if (i < 40000){ int k=i/200, c=i%200; W16d2[i] = __float2half_rn(ldf(aout,(size_t)c*600+200+k,fdt)); return; }
}

// f32 copy of entity rows (for scalar-load operand path) + per-node inverse norms
__global__ __launch_bounds__(128)
void k_cvt_en(const void* __restrict__ ent, const int* __restrict__ ifl,
              float* __restrict__ ENf, float* __restrict__ invn){
  __shared__ float part[2];
  const int n = blockIdx.x, t = threadIdx.x;
  const int fdt = ifl[1];
  float e = 0.f;
  if (t < 100) e = ldf(ent, (size_t)n*100 + t, fdt);
  float ss = e*e;
  #pragma unroll
  for (int o = 1; o < 64; o <<= 1) ss += __shfl_xor(ss, o);
  if ((t & 63) == 0) part[t >> 6] = ss;
  __syncthreads();
  if (t == 0) invn[n] = 1.f / fmaxf(sqrtf(part[0] + part[1]), 1e-12f);
  if (fdt != 0 && t < 100) ENf[(size_t)n*100 + t] = e;
}

// R1f[tt][t] = rtab[tt] @ a_rel.T ; sR1[tt][h]
__global__ __launch_bounds__(256)
void k_R1(const void* __restrict__ rtab, const void* __restrict__ ah, const int* __restrict__ ifl,
          const float* __restrict__ a2f, float* __restrict__ R1f, float* __restrict__ sR1){
  __shared__ float rt[100], ml[200];
  const int tt = blockIdx.x, t = threadIdx.x, fdt = ifl[1];
  if (t < 100) rt[t] = ldf(rtab,(size_t)tt*100+t,fdt);
  __syncthreads();
  if (t < 200){
    float R = 0.f;
    for (int k = 0; k < 100; ++k) R += rt[k]*ldf(ah,(size_t)t*300+200+k,fdt);
    R1f[tt*200+t] = R; ml[t] = R*a2f[t];
  }
  __syncthreads();
  if (t < 64){
    float s = 0.f;
    for (int q = t; q < 100; q += 64) s += ml[q];
    for (int o = 1; o < 64; o <<= 1) s += __shfl_xor(s, o);
    if (t == 0) sR1[tt*2] = s;
  } else if (t < 128){
    int l = t - 64;
    float s = 0.f;
    for (int q = 100 + l; q < 200; q += 64) s += ml[q];
    for (int o = 1; o < 64; o <<= 1) s += __shfl_xor(s, o);
    if (l == 0) sR1[tt*2+1] = s;
  }
}

// R2f[tt][t] = M2f[tt] @ a_rel2.T ; sR2[tt]
__global__ __launch_bounds__(256)
void k_R2(const float* __restrict__ M2f, const void* __restrict__ aout, const int* __restrict__ ifl,
          const float* __restrict__ a2of, float* __restrict__ R2f, float* __restrict__ sR2){
  __shared__ float mr[200], ml[200];
  const int tt = blockIdx.x, t = threadIdx.x, fdt = ifl[1];
  if (t < 200) mr[t] = M2f[tt*200+t];
  __syncthreads();
  if (t < 200){
    float R = 0.f;
    for (int k = 0; k < 200; ++k) R += mr[k]*ldf(aout,(size_t)t*600+400+k,fdt);
    R2f[tt*200+t] = R; ml[t] = R*a2of[t];
  }
  __syncthreads();
  if (t < 64){
    float s = 0.f;
    for (int q = t; q < 200; q += 64) s += ml[q];
    for (int o = 1; o < 64; o <<= 1) s += __shfl_xor(s, o);
    if (t == 0) sR2[tt] = s;
  }
}

// ---------------- CSR (packed: dst | type<<16) ----------------
__global__ void k_count(const void* __restrict__ el, const int* __restrict__ ifl, int* __restrict__ cnt){
  int e = blockIdx.x*256 + threadIdx.x;
  if (e >= E_EDGES) return;
  atomicAdd(&cnt[ild(el, e, ifl[0])], 1);
}
__global__ __launch_bounds__(256)
void k_scan(const int* __restrict__ cnt, int* __restrict__ offs){
  __shared__ int bs[256];
  int t = threadIdx.x;
  const int CH = (N_NODES + 255) / 256;
  int lo = t*CH, hi = min(lo+CH, N_NODES);
  int s = 0;
  for (int i = lo; i < hi; ++i) s += cnt[i];
  bs[t] = s;
  __syncthreads();
  for (int o = 1; o < 256; o <<= 1){
    int v = (t >= o) ? bs[t-o] : 0;
    __syncthreads();
    bs[t] += v;
    __syncthreads();
  }
  int base = (t == 0) ? 0 : bs[t-1];
  for (int i = lo; i < hi; ++i){ offs[i] = base; base += cnt[i]; }
  if (t == 255) offs[N_NODES] = bs[255];
}
__global__ void k_scatter(const void* __restrict__ el, const void* __restrict__ et,
                          const int* __restrict__ ifl, const int* __restrict__ offs,
                          int* __restrict__ fill, int* __restrict__ csr){
  int e = blockIdx.x*256 + threadIdx.x;
  if (e >= E_EDGES) return;
  int f = ifl[0];
  int a = ild(el, e, f);
  int pos = offs[a] + atomicAdd(&fill[a], 1);
  csr[pos] = ild(el, (size_t)E_EDGES + e, f) | (ild(et, e, f) << 16);
}

// flag = masked nodes + their neighbors
__global__ void k_flag(const int* __restrict__ b32, const int* __restrict__ offs,
                       const int* __restrict__ csr, int* __restrict__ nflag){
  const int i = blockIdx.x, t = threadIdx.x;
  const int n = b32[i*4 + 2];
  if (t == 0) nflag[n] = 1;
  for (int j = offs[n] + t; j < offs[n+1]; j += 256) nflag[csr[j] & 0xFFFF] = 1;
}
__global__ void k_compact(const int* __restrict__ nflag, int* __restrict__ fcnt, int* __restrict__ flist){
  int i = blockIdx.x*256 + threadIdx.x;
  if (i < N_NODES && nflag[i]) flist[atomicAdd(fcnt, 1)] = i;
}

// ---- 8-node/block matvec: D1 (K=100) ----
__global__ __launch_bounds__(256)
void k_D1b(const void* __restrict__ ent, const float* __restrict__ ENf, const int* __restrict__ ifl,
           const __half* __restrict__ W16d, const float* __restrict__ a2f,
           __half* __restrict__ D1, float* __restrict__ sD)
{
  __shared__ __half Wl[200*102];
  __shared__ float scr[4*16], outr[16];
  const int t = threadIdx.x;
  const int n0 = blockIdx.x*8;
  const int fdt = ifl[1];
  const unsigned int* Wg = (const unsigned int*)W16d;
  for (int idx = t; idx < 10000; idx += 256){
    unsigned int u = Wg[idx];
    int e = idx*2, k = e/200, c = e - k*200;
    __half2 h = __builtin_bit_cast(__half2, u);
    Wl[c*102+k] = h.x; Wl[(c+1)*102+k] = h.y;
  }
  __syncthreads();
  const float* ENp = (fdt == 0) ? (const float*)ent : ENf;
  const int col = (t < 200) ? t : 199;
  const bool act = t < 200;
  float acc[8] = {0,0,0,0,0,0,0,0};
  for (int k = 0; k < 100; k += 2){
    __half2 wh = *(const __half2*)&Wl[col*102 + k];
    float2 wf = __half22float2(wh);
    #pragma unroll
    for (int i = 0; i < 8; ++i){
      const float* ep = ENp + (size_t)(n0+i)*100 + k;
      acc[i] += ep[0]*wf.x + ep[1]*wf.y;
    }
  }
  float a2v = act ? a2f[col] : 0.f;
  float hv[16];
  #pragma unroll
  for (int i = 0; i < 8; ++i){
    if (act) D1[(size_t)(n0+i)*200 + col] = __float2half_rn(acc[i]);
    float m = acc[i]*a2v;
    hv[i*2]   = (col < 100) ? m : 0.f;
    hv[i*2+1] = (col < 100) ? 0.f : m;
  }
  blockRed<16>(hv, scr, outr);
  if (t < 16) sD[(size_t)(n0 + (t>>1))*2 + (t&1)] = outr[t];
}

// ---- 8-node/block matvec + epilogue: entities_upgraded & final l2norm output ----
__global__ __launch_bounds__(256)
void k_eufb(const void* __restrict__ ent, const float* __restrict__ ENf, const int* __restrict__ ifl,
            const __half* __restrict__ W16e, const float* __restrict__ invn,
            const int* __restrict__ midx, const float* __restrict__ x2m, char* __restrict__ dout)
{
  __shared__ __half Wl[200*102];
  __shared__ float scr[4*8], outr[8];
  const int t = threadIdx.x;
  const int n0 = blockIdx.x*8;
  const int fdt = ifl[1];
  const unsigned int* Wg = (const unsigned int*)W16e;
  for (int idx = t; idx < 10000; idx += 256){
    unsigned int u = Wg[idx];
    int e = idx*2, k = e/200, c = e - k*200;
    __half2 h = __builtin_bit_cast(__half2, u);
    Wl[c*102+k] = h.x; Wl[(c+1)*102+k] = h.y;
  }
  __syncthreads();
  const float* ENp = (fdt == 0) ? (const float*)ent : ENf;
  const int col = (t < 200) ? t : 199;
  const bool act = t < 200;
  float acc[8] = {0,0,0,0,0,0,0,0};
  for (int k = 0; k < 100; k += 2){
    __half2 wh = *(const __half2*)&Wl[col*102 + k];
    float2 wf = __half22float2(wh);
    #pragma unroll
    for (int i = 0; i < 8; ++i){
      const float* ep = ENp + (size_t)(n0+i)*100 + k;
      acc[i] += ep[0]*wf.x + ep[1]*wf.y;
    }
  }
  float val[8], ss[8];
  #pragma unroll
  for (int i = 0; i < 8; ++i){
    const int n = n0 + i;
    float v = acc[i]*invn[n];
    const int mi = midx[n];
    if (mi >= 0) v += x2m[(size_t)mi*200 + col];
    val[i] = act ? v : 0.f;
    ss[i] = val[i]*val[i];
  }
  blockRed<8>(ss, scr, outr);
  #pragma unroll
  for (int i = 0; i < 8; ++i){
    if (act){
      float r = 1.f / fmaxf(sqrtf(outr[i]), 1e-12f);
      stf(dout, (size_t)(n0+i)*200 + col, val[i]*r, fdt);
    }
  }
}

// ---- 8-node/block matvec over compacted flagged list: D2 (K=200, two LDS phases) ----
__global__ __launch_bounds__(256)
void k_D2b(const __half* __restrict__ x1, const int* __restrict__ flist, const int* __restrict__ fcnt,
           const __half* __restrict__ W16d2, const float* __restrict__ a2of,
           __half* __restrict__ D2, float* __restrict__ sD2)
{
  __shared__ __half Wl[200*102];
  __shared__ float scr[4*8], outr[8];
  const int t = threadIdx.x;
  const int base = blockIdx.x*8;
  const int cnt = fcnt[0];
  if (base >= cnt) return;
  int nd[8];
  #pragma unroll
  for (int i = 0; i < 8; ++i){ int j = base + i; nd[i] = flist[j < cnt ? j : cnt-1]; }
  const int col = (t < 200) ? t : 199;
  const bool act = t < 200;
  float acc[8] = {0,0,0,0,0,0,0,0};
  const unsigned int* Wg = (const unsigned int*)W16d2;
  #pragma unroll 1
  for (int p = 0; p < 2; ++p){
    if (p) __syncthreads();
    for (int idx = t; idx < 10000; idx += 256){
      unsigned int u = Wg[p*10000 + idx];
      int e = idx*2, k = e/200, c = e - k*200;
      __half2 h = __builtin_bit_cast(__half2, u);
      Wl[c*102+k] = h.x; Wl[(c+1)*102+k] = h.y;
    }
    __syncthreads();
    for (int kp = 0; kp < 100; kp += 2){
      __half2 wh = *(const __half2*)&Wl[col*102 + kp];
      float2 wf = __half22float2(wh);
      const int k = p*100 + kp;
      #pragma unroll
      for (int i = 0; i < 8; ++i){
        unsigned int u = *(const unsigned int*)(x1 + (size_t)nd[i]*200 + k);
        __half2 eh = __builtin_bit_cast(__half2, u);
        float2 ef = __half22float2(eh);
        acc[i] += ef.x*wf.x + ef.y*wf.y;
      }
    }
  }
  float a2v = act ? a2of[col] : 0.f;
  float ml[8];
  #pragma unroll
  for (int i = 0; i < 8; ++i){
    if (act) D2[(size_t)nd[i]*200 + col] = __float2half_rn(acc[i]);
    ml[i] = acc[i]*a2v;
  }
  blockRed<8>(ml, scr, outr);
  if (t < 8 && base + t < cnt) sD2[nd[t]] = outr[t];
}

// layer 1 aggregation, flagged nodes only
__global__ __launch_bounds__(256)
void k_x1(const void* __restrict__ ent, const float* __restrict__ ENf, const int* __restrict__ ifl,
          const int* __restrict__ nflag, const float* __restrict__ aTs, const float* __restrict__ a2f,
          const float* __restrict__ R1f, const float* __restrict__ sR1,
          const __half* __restrict__ D1, const float* __restrict__ sD,
          const int* __restrict__ offs, const int* __restrict__ csr, __half* __restrict__ x1)
{
  __shared__ float ml[200], sS2[2];
  const int n = blockIdx.x, t = threadIdx.x;
  if (!nflag[n]) return;
  const int fdt = ifl[1];
  const float* ENp = (fdt == 0) ? (const float*)ent : ENf;
  float S = 0.f;
  if (t < 200){
    const float* ep = ENp + (size_t)n*100;
    for (int k = 0; k < 100; ++k) S += ep[k]*aTs[k*200+t];
    ml[t] = S*a2f[t];
  }
  __syncthreads();
  if (t < 64){
    float s = 0.f;
    for (int q = t; q < 100; q += 64) s += ml[q];
    for (int o = 1; o < 64; o <<= 1) s += __shfl_xor(s, o);
    if (t == 0) sS2[0] = s;
  } else if (t < 128){
    int l = t - 64;
    float s = 0.f;
    for (int q = 100 + l; q < 200; q += 64) s += ml[q];
    for (int o = 1; o < 64; o <<= 1) s += __shfl_xor(s, o);
    if (l == 0) sS2[1] = s;
  }
  __syncthreads();
  if (t >= 200) return;
  const int h = (t >= 100) ? 1 : 0;
  const float sS = sS2[h];
  float acc = 0.f, W = 0.f;
  const int beg = offs[n], end = offs[n+1];
  for (int j = beg; j < end; ++j){
    int pk = csr[j];
    int v = pk & 0xFFFF, tt = pk >> 16;
    float d = __half2float(D1[(size_t)v*200 + t]);
    float r = R1f[tt*200 + t];
    float p = sS + sD[(size_t)v*2 + h] + sR1[tt*2 + h];
    float lk = p > 0.f ? p : 0.2f*p;
    float w = expf(-lk);
    acc += w*(d + r); W += w;
  }
  float hh = (S*W + acc) / (W + 1e-12f);
  x1[(size_t)n*200 + t] = __float2half_rn(hh > 0.f ? hh : (expf(hh) - 1.f));
}

// layer 2, masked nodes only
__global__ __launch_bounds__(256)
void k_x2m(const int* __restrict__ b32, const __half* __restrict__ x1, const float* __restrict__ aoTs,
           const float* __restrict__ a2of, const float* __restrict__ R2f, const float* __restrict__ sR2,
           const __half* __restrict__ D2, const float* __restrict__ sD2,
           const int* __restrict__ offs, const int* __restrict__ csr, float* __restrict__ x2m)
{
  __shared__ float xn[200], ml[200], sS2[1];
  const int i = blockIdx.x, t = threadIdx.x;
  const int n = b32[i*4 + 2];
  if (t < 200) xn[t] = __half2float(x1[(size_t)n*200 + t]);
  __syncthreads();
  float S = 0.f;
  if (t < 200){
    for (int k = 0; k < 200; ++k) S += xn[k]*aoTs[k*200+t];
    ml[t] = S*a2of[t];
  }
  __syncthreads();
  if (t < 64){
    float s = 0.f;
    for (int q = t; q < 200; q += 64) s += ml[q];
    for (int o = 1; o < 64; o <<= 1) s += __shfl_xor(s, o);
    if (t == 0) sS2[0] = s;
  }
  __syncthreads();
  if (t >= 200) return;
  const float sS = sS2[0];
  float acc = 0.f, W = 0.f;
  const int beg = offs[n], end = offs[n+1];
  for (int j = beg; j < end; ++j){
    int pk = csr[j];
    int v = pk & 0xFFFF, tt = pk >> 16;
    float d = __half2float(D2[(size_t)v*200 + t]);
    float r = R2f[tt*200 + t];
    float p = sS + sD2[v] + sR2[tt];
    float lk = p > 0.f ? p : 0.2f*p;
    float w = expf(-lk);
    acc += w*(d + r); W += w;
  }
  float hh = (S*W + acc) / (W + 1e-12f);
  x2m[(size_t)i*200 + t] = hh > 0.f ? hh : (expf(hh) - 1.f);
}

// ---------------- his_temp ----------------
__global__ __launch_bounds__(256)
void k_his(const void* __restrict__ binp, const void* __restrict__ wt, const void* __restrict__ bt,
           const int* __restrict__ ifl, char* __restrict__ dout)
{
  __shared__ float he[100];
  const int i = blockIdx.x, t = threadIdx.x;
  const int fdt = ifl[1];
  const size_t esz = (fdt == 0) ? 4 : 2;
  const double t2 = (double)ild(binp, (size_t)i*4 + 3, ifl[0]);
  if (t < 100){
    double a = t2 * (double)ldf(wt, t, fdt) + (double)ldf(bt, t, fdt);
    he[t] = (float)cos(a);
  }
  __syncthreads();
  void* out2 = dout + (size_t)10000000 * esz;
  const size_t base = (size_t)i * (B_BATCH*HDIM);
  for (int s = t; s < B_BATCH*HDIM; s += 256) stf(out2, base + s, he[s % 100], fdt);
}

// ---------------- launch ----------------
extern "C" void kernel_launch(void* const* d_in, const int* in_sizes, int n_in,
                              void* d_out, int out_size, void* d_ws, size_t ws_size,
                              hipStream_t stream)
{
  (void)in_sizes; (void)n_in; (void)out_size; (void)ws_size;
  const void* ent  = d_in[0];
  const void* rtab = d_in[1];
  const void* w_t2 = d_in[2];
  const void* b_t2 = d_in[3];
  const void* Went = d_in[4];
  const void* ah   = d_in[5];
  const void* a2h  = d_in[6];
  const void* Wrel = d_in[7];
  const void* aout = d_in[8];
  const void* a2o  = d_in[9];
  const void* elist = d_in[10];
  const void* etype = d_in[11];
  const void* binp  = d_in[12];

  int* ifl = (int*)d_ws;                         // [0]=int64 flag, [1]=float dtype
  int* b32 = (int*)((char*)d_ws + 256);          // 2048 ints

  char* dout = (char*)d_out;
  // ENf at [0,20MB): f32 copy of ent (16-bit dtypes only). k_eufb reads rows n0..n0+7
  // (bytes [n*400,(n+8)*400)) then writes out0 16-bit to the SAME bytes -> per-block
  // read-before-write, disjoint across blocks. In f32 mode ENf is unused (ent read directly).
  float* ENf = (float*)dout;
  // Region A [20MB,40MB): D1 then D2 (fp16).
  __half* D12 = (__half*)(dout + 20000000);
  // Region B [40MB,~66.5MB): consumed by kernels up to k_eufb; inside out1 for all dtypes.
  char* scr = dout + 40000000;
  size_t cur = 0;
  auto alloc = [&](size_t bytes) -> char* {
    char* p = scr + cur;
    cur = (cur + bytes + 255) & ~(size_t)255;
    return p;
  };
  __half* X1    = (__half*)alloc((size_t)N_NODES*200*2);   // 20 MB
  int*   csr    = (int*)alloc((size_t)E_EDGES*4);          // 3.2 MB
  int*   offs   = (int*)alloc((size_t)(N_NODES+1)*4);
  int*   cnt    = (int*)alloc((size_t)N_NODES*4);
  int*   midx   = (int*)alloc((size_t)N_NODES*4);
  int*   nflag  = (int*)alloc((size_t)N_NODES*4);
  int*   flist  = (int*)alloc((size_t)N_NODES*4);
  int*   fcnt   = (int*)alloc(256);
  float* invn   = (float*)alloc((size_t)N_NODES*4);
  float* M2f    = (float*)alloc((size_t)200*200*4);
  float* x2m    = (float*)alloc((size_t)B_BATCH*200*4);
  float* aTs    = (float*)alloc((size_t)100*200*4);
  float* aoTs   = (float*)alloc((size_t)200*200*4);
  float* R1f    = (float*)alloc((size_t)200*200*4);
  float* R2f    = (float*)alloc((size_t)200*200*4);
  float* sD     = (float*)alloc((size_t)N_NODES*2*4);
  float* sD2    = (float*)alloc((size_t)N_NODES*4);
  float* sR1    = (float*)alloc((size_t)200*2*4);
  float* sR2    = (float*)alloc((size_t)200*4);
  float* a2f    = (float*)alloc((size_t)200*4);
  float* a2of   = (float*)alloc((size_t)200*4);
  __half* W16e  = (__half*)alloc((size_t)100*200*2);
  __half* W16d  = (__half*)alloc((size_t)100*200*2);
  __half* W16d2 = (__half*)alloc((size_t)200*200*2);
  // total ~26.6 MB -> ends ~66.6 MB < 72.4 MB (min d_out at esize=2)

  const int EB = (E_EDGES + 255) / 256;
  const int NB = (N_NODES + 255) / 256;

  k_probe<<<dim3(1), dim3(64), 0, stream>>>((const unsigned short*)ent, (const unsigned int*)ent,
                                            (const unsigned int*)elist, ifl);
  k_cvtb <<<dim3(8), dim3(256), 0, stream>>>(binp, ifl, b32);
  k_fillm<<<dim3(NB), dim3(256), 0, stream>>>(midx, -1, N_NODES);
  k_mset <<<dim3(2), dim3(256), 0, stream>>>(b32, midx);
  k_trans<<<dim3(237), dim3(256), 0, stream>>>(ah, aout, a2h, a2o, ifl, aTs, aoTs, a2f, a2of);
  k_w16  <<<dim3(313), dim3(256), 0, stream>>>(Went, ah, aout, ifl, W16e, W16d, W16d2);
  k_cvt_en<<<dim3(N_NODES), dim3(128), 0, stream>>>(ent, ifl, ENf, invn);
  k_m2f  <<<dim3(157), dim3(256), 0, stream>>>(rtab, Wrel, etype, ifl, M2f);
  k_R1   <<<dim3(200), dim3(256), 0, stream>>>(rtab, ah, ifl, a2f, R1f, sR1);
  k_R2   <<<dim3(200), dim3(256), 0, stream>>>(M2f, aout, ifl, a2of, R2f, sR2);

  k_fillm<<<dim3(NB), dim3(256), 0, stream>>>(cnt, 0, N_NODES);
  k_count<<<dim3(EB), dim3(256), 0, stream>>>(elist, ifl, cnt);
  k_scan <<<dim3(1), dim3(256), 0, stream>>>(cnt, offs);
  k_fillm<<<dim3(NB), dim3(256), 0, stream>>>(cnt, 0, N_NODES);
  k_scatter<<<dim3(EB), dim3(256), 0, stream>>>(elist, etype, ifl, offs, cnt, csr);

  k_fillm<<<dim3(NB), dim3(256), 0, stream>>>(nflag, 0, N_NODES);
  k_flag <<<dim3(B_BATCH), dim3(256), 0, stream>>>(b32, offs, csr, nflag);
  k_fillm<<<dim3(1), dim3(256), 0, stream>>>(fcnt, 0, 1);
  k_compact<<<dim3(NB), dim3(256), 0, stream>>>(nflag, fcnt, flist);

  k_D1b<<<dim3(N_NODES/8), dim3(256), 0, stream>>>(ent, ENf, ifl, W16d, a2f, D12, sD);
  k_x1 <<<dim3(N_NODES), dim3(256), 0, stream>>>(ent, ENf, ifl, nflag, aTs, a2f, R1f, sR1, D12, sD, offs, csr, X1);
  k_D2b<<<dim3(N_NODES/8), dim3(256), 0, stream>>>(X1, flist, fcnt, W16d2, a2of, D12, sD2);
  k_x2m<<<dim3(B_BATCH), dim3(256), 0, stream>>>(b32, X1, aoTs, a2of, R2f, sR2, D12, sD2, offs, csr, x2m);
  k_eufb<<<dim3(N_NODES/8), dim3(256), 0, stream>>>(ent, ENf, ifl, W16e, invn, midx, x2m, dout);

  // LAST: overwrites all of out1 (incl. all scratch); reads only inputs + ifl
  k_his<<<dim3(B_BATCH), dim3(256), 0, stream>>>(binp, w_t2, b_t2, ifl, dout);
}